// Round 1
// baseline (268.647 us; speedup 1.0000x reference)
//
#include <hip/hip_runtime.h>

#define BB     64
#define TT     512
#define EE     128
#define NROWS  (BB * TT)     // 32768
#define PADIDX 1
#define OUTN   1000

__device__ __forceinline__ float tanh_fast(float v) {
    // exact at +-inf, ~1e-6 abs err elsewhere (v_exp_f32 based)
    return 1.0f - 2.0f / (__expf(2.0f * v) + 1.0f);
}

// ---------------------------------------------------------------------------
// Kernel 1: x[row][e] = tanh( sum_d C[row][d] * W[e][d] ),  s[row] = x . a
//   C segments: g=0 node_emb[starts] (PAD->0), g=1 path_emb[paths],
//               g=2 node_emb[ends] (PAD->0)
// Block: 128 rows x 128 cols, 256 threads, thread tile 8x8.
// ---------------------------------------------------------------------------
__global__ __launch_bounds__(256, 1)
void k_gemm_x(const int* __restrict__ starts, const int* __restrict__ paths,
              const int* __restrict__ ends,
              const float* __restrict__ node_emb, const float* __restrict__ path_emb,
              const float* __restrict__ W, const float* __restrict__ a,
              float* __restrict__ x, float* __restrict__ s)
{
    __shared__ float Asg[128][132];   // gathered rows, padded stride
    __shared__ float Wsg[128][132];   // Wsg[c][k] = W[c][g*128+k]

    const int tid = threadIdx.x;
    const int r0  = blockIdx.x * 128;
    const int tx  = tid & 15;         // col group
    const int ty  = tid >> 4;         // row group

    float acc[8][8];
#pragma unroll
    for (int i = 0; i < 8; ++i)
#pragma unroll
        for (int j = 0; j < 8; ++j) acc[i][j] = 0.0f;

    for (int g = 0; g < 3; ++g) {
        const int*   idxs    = (g == 0) ? starts : (g == 1) ? paths : ends;
        const float* emb     = (g == 1) ? path_emb : node_emb;
        const bool   is_node = (g != 1);

        // ---- load A tile (gather) into regs: 16 float4 per thread ----
        float4 tA[16];
#pragma unroll
        for (int it = 0; it < 16; ++it) {
            const int slot = it * 256 + tid;       // rl*32 + cq
            const int rl   = slot >> 5;
            const int cq   = slot & 31;
            const int idx  = idxs[r0 + rl];
            float4 vv = *((const float4*)(emb + (size_t)idx * EE) + cq);
            if (is_node && idx == PADIDX) { vv.x = 0.f; vv.y = 0.f; vv.z = 0.f; vv.w = 0.f; }
            tA[it] = vv;
        }
        // ---- load W segment into regs ----
        float4 tW[16];
#pragma unroll
        for (int it = 0; it < 16; ++it) {
            const int slot = it * 256 + tid;       // c*32 + cq
            const int c    = slot >> 5;
            const int cq   = slot & 31;
            tW[it] = *((const float4*)(W + c * 384 + g * 128) + cq);
        }

        __syncthreads();   // previous segment's compute must be done before LDS overwrite
#pragma unroll
        for (int it = 0; it < 16; ++it) {
            const int slot = it * 256 + tid;
            *(float4*)&Asg[slot >> 5][(slot & 31) * 4] = tA[it];
        }
#pragma unroll
        for (int it = 0; it < 16; ++it) {
            const int slot = it * 256 + tid;
            *(float4*)&Wsg[slot >> 5][(slot & 31) * 4] = tW[it];
        }
        __syncthreads();

        // ---- compute: 128-deep K, 4-wide vector steps ----
#pragma unroll 2
        for (int k0 = 0; k0 < 128; k0 += 4) {
            float4 av[8], wv[8];
#pragma unroll
            for (int i = 0; i < 8; ++i) av[i] = *(const float4*)&Asg[ty + 16 * i][k0];
#pragma unroll
            for (int j = 0; j < 8; ++j) wv[j] = *(const float4*)&Wsg[tx + 16 * j][k0];
#pragma unroll
            for (int i = 0; i < 8; ++i)
#pragma unroll
                for (int j = 0; j < 8; ++j) {
                    acc[i][j] = fmaf(av[i].x, wv[j].x, acc[i][j]);
                    acc[i][j] = fmaf(av[i].y, wv[j].y, acc[i][j]);
                    acc[i][j] = fmaf(av[i].z, wv[j].z, acc[i][j]);
                    acc[i][j] = fmaf(av[i].w, wv[j].w, acc[i][j]);
                }
        }
    }

    // ---- epilogue: tanh, store x, reduce s = x.a ----
    float a_reg[8];
#pragma unroll
    for (int j = 0; j < 8; ++j) a_reg[j] = a[tx + 16 * j];

#pragma unroll
    for (int i = 0; i < 8; ++i) {
        const int r = r0 + ty + 16 * i;
        float part = 0.0f;
#pragma unroll
        for (int j = 0; j < 8; ++j) {
            const float t = tanh_fast(acc[i][j]);
            x[(size_t)r * EE + tx + 16 * j] = t;
            part = fmaf(t, a_reg[j], part);
        }
        // reduce across the 16 tx lanes (same ty group, contiguous lanes)
#pragma unroll
        for (int m = 1; m < 16; m <<= 1) part += __shfl_xor(part, m, 64);
        if (tx == 0) s[r] = part;
    }
}

// ---------------------------------------------------------------------------
// Kernel 2: per-b softmax over T (full T, no mask), then masked weighted sum
//           v[b][e] = sum_t  softmax(s)[t] * (t < len) * x[b][t][e]
// ---------------------------------------------------------------------------
__global__ __launch_bounds__(256)
void k_attn(const float* __restrict__ s, const int* __restrict__ length,
            const float* __restrict__ x, float* __restrict__ v)
{
    __shared__ float sw[TT];
    __shared__ float red[256];

    const int b   = blockIdx.x;
    const int tid = threadIdx.x;

    sw[tid]       = s[b * TT + tid];
    sw[tid + 256] = s[b * TT + tid + 256];
    __syncthreads();

    // max-reduce
    float m = fmaxf(sw[tid], sw[tid + 256]);
    red[tid] = m;
    __syncthreads();
    for (int st = 128; st > 0; st >>= 1) {
        if (tid < st) red[tid] = fmaxf(red[tid], red[tid + st]);
        __syncthreads();
    }
    const float mx = red[0];
    __syncthreads();

    // exp + sum-reduce
    const float e0 = __expf(sw[tid] - mx);
    const float e1 = __expf(sw[tid + 256] - mx);
    red[tid] = e0 + e1;
    __syncthreads();
    for (int st = 128; st > 0; st >>= 1) {
        if (tid < st) red[tid] += red[tid + st];
        __syncthreads();
    }
    const float inv = 1.0f / red[0];
    const int   len = length[b];
    __syncthreads();

    sw[tid]       = (tid < len)       ? e0 * inv : 0.0f;
    sw[tid + 256] = (tid + 256 < len) ? e1 * inv : 0.0f;
    __syncthreads();

    // weighted sum over t; thread = (e, half)
    const int e    = tid & 127;
    const int half = tid >> 7;
    const float* xb = x + (size_t)b * TT * EE;
    float acc = 0.0f;
#pragma unroll 8
    for (int t = half * 256; t < half * 256 + 256; ++t)
        acc = fmaf(sw[t], xb[t * EE + e], acc);

    red[tid] = acc;
    __syncthreads();
    if (tid < 128) v[b * EE + tid] = red[tid] + red[tid + 128];
}

// ---------------------------------------------------------------------------
// Kernel 3: out[b][o] = v[b] . out_W[o] + out_b[o]
// flat id = o*64 + b  -> out_W row is wave-uniform (scalar-broadcast),
// v is 32KB (L1/L2 resident)
// ---------------------------------------------------------------------------
__global__ __launch_bounds__(256)
void k_out(const float* __restrict__ v, const float* __restrict__ out_W,
           const float* __restrict__ out_b, float* __restrict__ out)
{
    const int id = blockIdx.x * 256 + threadIdx.x;   // 0..63999
    const int o  = id >> 6;
    const int bb = id & 63;

    const float4* vr = (const float4*)(v + bb * EE);
    const float4* wr = (const float4*)(out_W + o * EE);
    float acc = 0.0f;
#pragma unroll 8
    for (int q = 0; q < 32; ++q) {
        const float4 a4 = vr[q];
        const float4 b4 = wr[q];
        acc = fmaf(a4.x, b4.x, acc);
        acc = fmaf(a4.y, b4.y, acc);
        acc = fmaf(a4.z, b4.z, acc);
        acc = fmaf(a4.w, b4.w, acc);
    }
    out[bb * OUTN + o] = acc + out_b[o];
}

extern "C" void kernel_launch(void* const* d_in, const int* in_sizes, int n_in,
                              void* d_out, int out_size, void* d_ws, size_t ws_size,
                              hipStream_t stream)
{
    const int*   starts   = (const int*)d_in[0];
    const int*   paths    = (const int*)d_in[1];
    const int*   ends     = (const int*)d_in[2];
    const int*   length   = (const int*)d_in[3];
    const float* node_emb = (const float*)d_in[4];
    const float* path_emb = (const float*)d_in[5];
    const float* W        = (const float*)d_in[6];
    const float* a        = (const float*)d_in[7];
    const float* out_W    = (const float*)d_in[8];
    const float* out_b    = (const float*)d_in[9];
    float*       out      = (float*)d_out;

    // workspace layout (fp32): x[32768*128] | s[32768] | v[64*128]  ~= 16.9 MB
    float* x = (float*)d_ws;
    float* s = x + (size_t)NROWS * EE;
    float* v = s + NROWS;

    k_gemm_x<<<NROWS / 128, 256, 0, stream>>>(starts, paths, ends,
                                              node_emb, path_emb, W, a, x, s);
    k_attn<<<BB, 256, 0, stream>>>(s, length, x, v);
    k_out<<<(BB * OUTN) / 256, 256, 0, stream>>>(v, out_W, out_b, out);
}

// Round 2
// 220.994 us; speedup vs baseline: 1.2156x; 1.2156x over previous
//
#include <hip/hip_runtime.h>

#define BB     64
#define TT     512
#define EE     128
#define NROWS  (BB * TT)     // 32768
#define PADIDX 1
#define OUTN   1000

typedef __attribute__((ext_vector_type(8)))  short short8;
typedef __attribute__((ext_vector_type(16))) float f32x16;

__device__ __forceinline__ float tanh_fast(float v) {
    return 1.0f - 2.0f / (__expf(2.0f * v) + 1.0f);
}

__device__ __forceinline__ unsigned short f2bf(float f) {
    unsigned int u = __float_as_uint(f);
    u += 0x7fffu + ((u >> 16) & 1u);          // RNE
    return (unsigned short)(u >> 16);
}
__device__ __forceinline__ float bf2f(unsigned short h) {
    return __uint_as_float(((unsigned int)h) << 16);
}

// ---------------------------------------------------------------------------
// Kernel 1: x = tanh(C @ W^T), s = x . a     via split-bf16 MFMA (3-product)
//   C[m][k]: k<128 node_emb[starts] (PAD->0), k<256 path_emb[paths],
//            else node_emb[ends] (PAD->0)
// Block: 128 rows x 128 cols, 256 thr (4 waves as 2x2, wave tile 64x64),
// K staged in 6 steps of 64. LDS tiles XOR-swizzled (G4: row&7 << 4).
// ---------------------------------------------------------------------------
__global__ __launch_bounds__(256, 1)
void k_gemm_x(const int* __restrict__ starts, const int* __restrict__ paths,
              const int* __restrict__ ends,
              const float* __restrict__ node_emb, const float* __restrict__ path_emb,
              const float* __restrict__ W, const float* __restrict__ a,
              float* __restrict__ x, float* __restrict__ s)
{
    __shared__ __align__(16) unsigned short Ah[128 * 64];
    __shared__ __align__(16) unsigned short Al[128 * 64];
    __shared__ __align__(16) unsigned short Wh[128 * 64];
    __shared__ __align__(16) unsigned short Wl[128 * 64];
    __shared__ int   idx_lds[3][128];
    __shared__ float s_red[128][2];

    const int tid = threadIdx.x;
    const int r0  = blockIdx.x * 128;

    if (tid < 128) {
        idx_lds[0][tid] = starts[r0 + tid];
        idx_lds[1][tid] = paths [r0 + tid];
        idx_lds[2][tid] = ends  [r0 + tid];
    }

    const int q    = tid & 15;          // float4 column within 64-k
    const int ty   = tid >> 4;          // 0..15
    const int lane = tid & 63;
    const int wid  = tid >> 6;
    const int wm   = wid >> 1;          // 2x2 wave grid
    const int wn   = wid & 1;
    const int fr   = lane & 31;         // frag row (A) / col (B)
    const int fkb  = (lane >> 5) * 16;  // byte offset of 8-bf16 group (k-half)

    f32x16 acc[2][2];
#pragma unroll
    for (int mi = 0; mi < 2; ++mi)
#pragma unroll
        for (int ni = 0; ni < 2; ++ni)
#pragma unroll
            for (int i = 0; i < 16; ++i) acc[mi][ni][i] = 0.0f;

    float4 va[8], vw[8];

    __syncthreads();   // idx_lds ready

#define LOAD_STAGE(T) do {                                                      \
    const int seg_ = (T) >> 1;                                                  \
    const int off_ = ((T) & 1) * 64;                                            \
    const float* emb_ = (seg_ == 1) ? path_emb : node_emb;                      \
    const bool isn_ = (seg_ != 1);                                              \
    _Pragma("unroll")                                                           \
    for (int it = 0; it < 8; ++it) {                                            \
        const int row_ = it * 16 + ty;                                          \
        const int idx_ = idx_lds[seg_][row_];                                   \
        va[it] = *((const float4*)(emb_ + (size_t)idx_ * EE + off_) + q);       \
        if (isn_ && idx_ == PADIDX) { va[it].x = 0.f; va[it].y = 0.f;           \
                                      va[it].z = 0.f; va[it].w = 0.f; }         \
        vw[it] = *((const float4*)(W + row_ * 384 + (T) * 64) + q);             \
    }                                                                           \
} while (0)

#define CVT_WRITE() do {                                                        \
    _Pragma("unroll")                                                           \
    for (int it = 0; it < 8; ++it) {                                            \
        const int row_  = it * 16 + ty;                                         \
        const int boff_ = row_ * 128 + ((q * 8) ^ ((row_ & 7) << 4));           \
        {                                                                       \
            const unsigned short h0 = f2bf(va[it].x), h1 = f2bf(va[it].y);      \
            const unsigned short h2 = f2bf(va[it].z), h3 = f2bf(va[it].w);      \
            uint2 hp; hp.x = (unsigned)h0 | ((unsigned)h1 << 16);               \
                      hp.y = (unsigned)h2 | ((unsigned)h3 << 16);               \
            *(uint2*)((char*)Ah + boff_) = hp;                                  \
            const unsigned short l0 = f2bf(va[it].x - bf2f(h0));                \
            const unsigned short l1 = f2bf(va[it].y - bf2f(h1));                \
            const unsigned short l2 = f2bf(va[it].z - bf2f(h2));                \
            const unsigned short l3 = f2bf(va[it].w - bf2f(h3));                \
            uint2 lp; lp.x = (unsigned)l0 | ((unsigned)l1 << 16);               \
                      lp.y = (unsigned)l2 | ((unsigned)l3 << 16);               \
            *(uint2*)((char*)Al + boff_) = lp;                                  \
        }                                                                       \
        {                                                                       \
            const unsigned short h0 = f2bf(vw[it].x), h1 = f2bf(vw[it].y);      \
            const unsigned short h2 = f2bf(vw[it].z), h3 = f2bf(vw[it].w);      \
            uint2 hp; hp.x = (unsigned)h0 | ((unsigned)h1 << 16);               \
                      hp.y = (unsigned)h2 | ((unsigned)h3 << 16);               \
            *(uint2*)((char*)Wh + boff_) = hp;                                  \
            const unsigned short l0 = f2bf(vw[it].x - bf2f(h0));                \
            const unsigned short l1 = f2bf(vw[it].y - bf2f(h1));                \
            const unsigned short l2 = f2bf(vw[it].z - bf2f(h2));                \
            const unsigned short l3 = f2bf(vw[it].w - bf2f(h3));                \
            uint2 lp; lp.x = (unsigned)l0 | ((unsigned)l1 << 16);               \
                      lp.y = (unsigned)l2 | ((unsigned)l3 << 16);               \
            *(uint2*)((char*)Wl + boff_) = lp;                                  \
        }                                                                       \
    }                                                                           \
} while (0)

#define COMPUTE() do {                                                          \
    _Pragma("unroll")                                                           \
    for (int ksub = 0; ksub < 4; ++ksub) {                                      \
        short8 ah[2], al2[2], bh[2], bl2[2];                                    \
        _Pragma("unroll")                                                       \
        for (int mi = 0; mi < 2; ++mi) {                                        \
            const int row_  = wm * 64 + mi * 32 + fr;                           \
            const int boff_ = row_ * 128 + ((ksub * 32 + fkb) ^ ((row_ & 7) << 4)); \
            ah[mi]  = *(const short8*)((const char*)Ah + boff_);                \
            al2[mi] = *(const short8*)((const char*)Al + boff_);                \
        }                                                                       \
        _Pragma("unroll")                                                       \
        for (int ni = 0; ni < 2; ++ni) {                                        \
            const int row_  = wn * 64 + ni * 32 + fr;                           \
            const int boff_ = row_ * 128 + ((ksub * 32 + fkb) ^ ((row_ & 7) << 4)); \
            bh[ni]  = *(const short8*)((const char*)Wh + boff_);                \
            bl2[ni] = *(const short8*)((const char*)Wl + boff_);                \
        }                                                                       \
        _Pragma("unroll")                                                       \
        for (int mi = 0; mi < 2; ++mi)                                          \
        _Pragma("unroll")                                                       \
        for (int ni = 0; ni < 2; ++ni) {                                        \
            acc[mi][ni] = __builtin_amdgcn_mfma_f32_32x32x16_bf16(ah[mi],  bh[ni],  acc[mi][ni], 0, 0, 0); \
            acc[mi][ni] = __builtin_amdgcn_mfma_f32_32x32x16_bf16(ah[mi],  bl2[ni], acc[mi][ni], 0, 0, 0); \
            acc[mi][ni] = __builtin_amdgcn_mfma_f32_32x32x16_bf16(al2[mi], bh[ni],  acc[mi][ni], 0, 0, 0); \
        }                                                                       \
    }                                                                           \
} while (0)

    // prologue: stage 0
    LOAD_STAGE(0);
    CVT_WRITE();
    __syncthreads();

    for (int t = 0; t < 6; ++t) {
        if (t < 5) LOAD_STAGE(t + 1);   // issue next gathers early (overlap MFMA)
        COMPUTE();
        __syncthreads();                // all waves done reading LDS
        if (t < 5) { CVT_WRITE(); __syncthreads(); }
    }

    // epilogue: tanh, store x, s = x.a
    const float a0 = a[wn * 64 + fr];
    const float a1 = a[wn * 64 + 32 + fr];
    const int hi_half = lane >> 5;

#pragma unroll
    for (int mi = 0; mi < 2; ++mi) {
        float sp[16];
#pragma unroll
        for (int r = 0; r < 16; ++r) sp[r] = 0.0f;
#pragma unroll
        for (int ni = 0; ni < 2; ++ni) {
            const float ac  = (ni == 0) ? a0 : a1;
            const int   col = wn * 64 + ni * 32 + fr;
#pragma unroll
            for (int r = 0; r < 16; ++r) {
                const int rowl = (r & 3) + 8 * (r >> 2) + 4 * hi_half;
                const float tv = tanh_fast(acc[mi][ni][r]);
                x[(size_t)(r0 + wm * 64 + mi * 32 + rowl) * EE + col] = tv;
                sp[r] = fmaf(tv, ac, sp[r]);
            }
        }
#pragma unroll
        for (int m = 1; m < 32; m <<= 1)
#pragma unroll
            for (int r = 0; r < 16; ++r) sp[r] += __shfl_xor(sp[r], m, 64);
        if (fr == 0) {
#pragma unroll
            for (int r = 0; r < 16; ++r) {
                const int rowl = (r & 3) + 8 * (r >> 2) + 4 * hi_half;
                s_red[wm * 64 + mi * 32 + rowl][wn] = sp[r];
            }
        }
    }
    __syncthreads();
    if (tid < 128) s[r0 + tid] = s_red[tid][0] + s_red[tid][1];
}

// ---------------------------------------------------------------------------
// Kernel 2: per-b softmax over full T, mask t<len, weighted sum of x.
// Grid 256: block = (b, 32-col e-chunk). All CUs participate in x read.
// ---------------------------------------------------------------------------
__global__ __launch_bounds__(256)
void k_attn(const float* __restrict__ s, const int* __restrict__ length,
            const float* __restrict__ x, float* __restrict__ v)
{
    __shared__ float sw[TT];
    __shared__ float red[256];

    const int b   = blockIdx.x >> 2;
    const int ec  = blockIdx.x & 3;
    const int tid = threadIdx.x;

    const float s0 = s[b * TT + tid];
    const float s1 = s[b * TT + 256 + tid];

    red[tid] = fmaxf(s0, s1);
    __syncthreads();
    for (int st = 128; st > 0; st >>= 1) {
        if (tid < st) red[tid] = fmaxf(red[tid], red[tid + st]);
        __syncthreads();
    }
    const float mx = red[0];
    __syncthreads();

    const float e0 = __expf(s0 - mx);
    const float e1 = __expf(s1 - mx);
    red[tid] = e0 + e1;
    __syncthreads();
    for (int st = 128; st > 0; st >>= 1) {
        if (tid < st) red[tid] += red[tid + st];
        __syncthreads();
    }
    const float inv = 1.0f / red[0];
    const int   len = length[b];
    __syncthreads();

    sw[tid]       = (tid < len)       ? e0 * inv : 0.0f;
    sw[tid + 256] = (tid + 256 < len) ? e1 * inv : 0.0f;
    __syncthreads();

    const int e  = ec * 32 + (tid & 31);
    const int tp = tid >> 5;
    const float* xb = x + (size_t)b * TT * EE;
    float acc = 0.0f;
#pragma unroll 8
    for (int t = tp; t < TT; t += 8)
        acc = fmaf(sw[t], xb[(size_t)t * EE + e], acc);

    red[tid] = acc;
    __syncthreads();
    if (tid < 32) {
        float r2 = 0.0f;
#pragma unroll
        for (int k = 0; k < 8; ++k) r2 += red[k * 32 + tid];
        v[b * EE + ec * 32 + tid] = r2;
    }
}

// ---------------------------------------------------------------------------
// Kernel 3: out[b][o] = v[b] . out_W[o] + out_b[o]
// ---------------------------------------------------------------------------
__global__ __launch_bounds__(256)
void k_out(const float* __restrict__ v, const float* __restrict__ out_W,
           const float* __restrict__ out_b, float* __restrict__ out)
{
    const int id = blockIdx.x * 256 + threadIdx.x;   // 0..63999
    const int o  = id >> 6;
    const int bb = id & 63;

    const float4* vr = (const float4*)(v + bb * EE);
    const float4* wr = (const float4*)(out_W + o * EE);
    float acc = 0.0f;
#pragma unroll 8
    for (int qq = 0; qq < 32; ++qq) {
        const float4 a4 = vr[qq];
        const float4 b4 = wr[qq];
        acc = fmaf(a4.x, b4.x, acc);
        acc = fmaf(a4.y, b4.y, acc);
        acc = fmaf(a4.z, b4.z, acc);
        acc = fmaf(a4.w, b4.w, acc);
    }
    out[bb * OUTN + o] = acc + out_b[o];
}

extern "C" void kernel_launch(void* const* d_in, const int* in_sizes, int n_in,
                              void* d_out, int out_size, void* d_ws, size_t ws_size,
                              hipStream_t stream)
{
    const int*   starts   = (const int*)d_in[0];
    const int*   paths    = (const int*)d_in[1];
    const int*   ends     = (const int*)d_in[2];
    const int*   length   = (const int*)d_in[3];
    const float* node_emb = (const float*)d_in[4];
    const float* path_emb = (const float*)d_in[5];
    const float* W        = (const float*)d_in[6];
    const float* a        = (const float*)d_in[7];
    const float* out_W    = (const float*)d_in[8];
    const float* out_b    = (const float*)d_in[9];
    float*       out      = (float*)d_out;

    float* x = (float*)d_ws;                    // [32768][128]
    float* s = x + (size_t)NROWS * EE;          // [32768]
    float* v = s + NROWS;                       // [64][128]

    k_gemm_x<<<NROWS / 128, 256, 0, stream>>>(starts, paths, ends,
                                              node_emb, path_emb, W, a, x, s);
    k_attn<<<BB * 4, 256, 0, stream>>>(s, length, x, v);
    k_out<<<(BB * OUTN) / 256, 256, 0, stream>>>(v, out_W, out_b, out);
}

// Round 4
// 208.980 us; speedup vs baseline: 1.2855x; 1.0575x over previous
//
#include <hip/hip_runtime.h>
#include <hip/hip_bf16.h>

#define BB     64
#define TT     512
#define EE     128
#define NROWS  (BB * TT)     // 32768
#define PADIDX 1
#define OUTN   1000

typedef __attribute__((ext_vector_type(8)))  short short8;
typedef __attribute__((ext_vector_type(16))) float f32x16;

__device__ __forceinline__ float tanh_fast(float v) {
    return 1.0f - 2.0f / (__expf(2.0f * v) + 1.0f);
}

// split f into bf16 hi (RNE) + bf16 lo (truncated residual): err <= 2^-17 |f|
__device__ __forceinline__ void split8(float4 a0, float4 a1, short8& hi, short8& lo) {
    float f[8] = {a0.x, a0.y, a0.z, a0.w, a1.x, a1.y, a1.z, a1.w};
#pragma unroll
    for (int i = 0; i < 8; ++i) {
        unsigned u = __float_as_uint(f[i]);
        unsigned r = (u + (0x7fffu + ((u >> 16) & 1u))) & 0xffff0000u;
        hi[i] = (short)(r >> 16);
        lo[i] = (short)(__float_as_uint(f[i] - __uint_as_float(r)) >> 16);
    }
}

__device__ __forceinline__ void gl_lds16(const void* g, void* l) {
    __builtin_amdgcn_global_load_lds((const __attribute__((address_space(1))) void*)g,
                                     (__attribute__((address_space(3))) void*)l, 16, 0, 0);
}

// ---------------------------------------------------------------------------
// k_prep: W [128][384] fp32 -> per-stage swizzled bf16 hi/lo LDS images.
// Image stage t: byte (e*128 + ((2k) ^ ((e&7)<<4))) holds bf16 of W[e][t*64+k].
// ---------------------------------------------------------------------------
__global__ __launch_bounds__(256)
void k_prep(const float* __restrict__ W, unsigned short* __restrict__ Whg,
            unsigned short* __restrict__ Wlg)
{
    const int id = blockIdx.x * 256 + threadIdx.x;   // exactly 49152
    const int e  = id & 127;
    const int d  = id >> 7;                          // 0..383
    const float v = W[e * 384 + d];
    const int t = d >> 6, k = d & 63;

    unsigned u = __float_as_uint(v);
    unsigned r = (u + (0x7fffu + ((u >> 16) & 1u))) & 0xffff0000u;
    const unsigned short h = (unsigned short)(r >> 16);
    const unsigned short l = (unsigned short)(__float_as_uint(v - __uint_as_float(r)) >> 16);

    const int boff = t * 16384 + e * 128 + ((k * 2) ^ ((e & 7) << 4));
    *(unsigned short*)((char*)Whg + boff) = h;
    *(unsigned short*)((char*)Wlg + boff) = l;
}

// ---------------------------------------------------------------------------
// Kernel 1: x = tanh(C @ W^T), s = x . a   (split-bf16 3-product MFMA)
// 256 blocks x 256 thr (4 waves, 2x2), BM=128, K in 6 stages of 64.
// A: fp32 via global_load_lds (source-swizzled), double-buffered.
// W: bf16 hi/lo stage images via linear global_load_lds, double-buffered.
// Counted vmcnt(16) keeps next stage's 16 loads in flight across barriers.
// ---------------------------------------------------------------------------
__global__ __launch_bounds__(256, 1)
void k_gemm_x(const int* __restrict__ starts, const int* __restrict__ paths,
              const int* __restrict__ ends,
              const float* __restrict__ node_emb, const float* __restrict__ path_emb,
              const unsigned short* __restrict__ Whg, const unsigned short* __restrict__ Wlg,
              const float* __restrict__ a, float* __restrict__ x, float* __restrict__ s)
{
    extern __shared__ char smem[];
    float*          Af      = (float*)smem;                       // [2][128*64] fp32
    unsigned short* Wh      = (unsigned short*)(smem + 65536);    // [2][128*64] bf16
    unsigned short* Wl      = (unsigned short*)(smem + 98304);    // [2][128*64] bf16
    int*            idx_lds = (int*)(smem + 131072);              // [3][128]
    float*          s_red   = (float*)(smem + 132608);            // [128][2]

    const int tid = threadIdx.x;
    const int r0  = blockIdx.x * 128;

    if (tid < 128) {
        idx_lds[0 * 128 + tid] = starts[r0 + tid];
        idx_lds[1 * 128 + tid] = paths [r0 + tid];
        idx_lds[2 * 128 + tid] = ends  [r0 + tid];
    }

    const int lane = tid & 63;
    const int w    = tid >> 6;          // wave id 0..3
    const int wm   = w >> 1;            // 2x2 wave grid
    const int wn   = w & 1;
    const int fr   = lane & 31;         // frag row (A) / col (B)
    const int kh   = lane >> 5;         // k-half

    f32x16 acc[2][2];
#pragma unroll
    for (int mi = 0; mi < 2; ++mi)
#pragma unroll
        for (int ni = 0; ni < 2; ++ni)
#pragma unroll
            for (int i = 0; i < 16; ++i) acc[mi][ni][i] = 0.0f;

    __syncthreads();   // idx_lds ready

    // PAD flags for this thread's two A-fragment rows (fixed across stages)
    bool p0[2], p2[2];
#pragma unroll
    for (int mi = 0; mi < 2; ++mi) {
        const int rm = wm * 64 + mi * 32 + fr;
        p0[mi] = (idx_lds[0 * 128 + rm] == PADIDX);
        p2[mi] = (idx_lds[2 * 128 + rm] == PADIDX);
    }

#define ISSUE(T) do {                                                           \
    const int   seg_  = (T) >> 1;                                               \
    const char* embc_ = (const char*)((seg_ == 1) ? path_emb : node_emb);       \
    char*       afb_  = (char*)Af + (((T) & 1) ? 32768 : 0);                    \
    _Pragma("unroll")                                                           \
    for (int it = 0; it < 8; ++it) {                                            \
        const int row_ = w * 32 + it * 4 + (lane >> 4);                         \
        const int idx_ = idx_lds[seg_ * 128 + row_];                            \
        const char* src_ = embc_ + (size_t)idx_ * 512 + ((T) & 1) * 256         \
                         + (((lane & 15) * 16) ^ ((row_ & 7) << 4));            \
        gl_lds16(src_, afb_ + (w * 32 + it * 4) * 256);                         \
    }                                                                           \
    char* whb_ = (char*)Wh + (((T) & 1) ? 16384 : 0);                           \
    char* wlb_ = (char*)Wl + (((T) & 1) ? 16384 : 0);                           \
    _Pragma("unroll")                                                           \
    for (int rr = 0; rr < 4; ++rr) {                                            \
        const int o_ = rr * 4096 + w * 1024;                                    \
        gl_lds16((const char*)Whg + (T) * 16384 + o_ + lane * 16, whb_ + o_);   \
        gl_lds16((const char*)Wlg + (T) * 16384 + o_ + lane * 16, wlb_ + o_);   \
    }                                                                           \
} while (0)

#define COMPUTE(T) do {                                                         \
    const char* afc_ = (const char*)Af + (((T) & 1) ? 32768 : 0);               \
    const char* whc_ = (const char*)Wh + (((T) & 1) ? 16384 : 0);               \
    const char* wlc_ = (const char*)Wl + (((T) & 1) ? 16384 : 0);               \
    _Pragma("unroll")                                                           \
    for (int ksub = 0; ksub < 4; ++ksub) {                                      \
        short8 ah[2], al[2], bh[2], bl[2];                                      \
        _Pragma("unroll")                                                       \
        for (int mi = 0; mi < 2; ++mi) {                                        \
            const int row_ = wm * 64 + mi * 32 + fr;                            \
            const int swz_ = (row_ & 7) << 4;                                   \
            const int k0b_ = ksub * 64 + kh * 32;                               \
            float4 a0 = *(const float4*)(afc_ + row_ * 256 + (k0b_ ^ swz_));    \
            float4 a1 = *(const float4*)(afc_ + row_ * 256 + ((k0b_ + 16) ^ swz_)); \
            const bool pad_ = ((T) < 2) ? p0[mi] : (((T) >= 4) ? p2[mi] : false); \
            if (pad_) { a0 = make_float4(0.f, 0.f, 0.f, 0.f); a1 = a0; }        \
            split8(a0, a1, ah[mi], al[mi]);                                     \
        }                                                                       \
        _Pragma("unroll")                                                       \
        for (int ni = 0; ni < 2; ++ni) {                                        \
            const int e_ = wn * 64 + ni * 32 + fr;                              \
            const int bo_ = e_ * 128 + ((ksub * 32 + kh * 16) ^ ((e_ & 7) << 4)); \
            bh[ni] = *(const short8*)(whc_ + bo_);                              \
            bl[ni] = *(const short8*)(wlc_ + bo_);                              \
        }                                                                       \
        _Pragma("unroll")                                                       \
        for (int mi = 0; mi < 2; ++mi)                                          \
        _Pragma("unroll")                                                       \
        for (int ni = 0; ni < 2; ++ni) {                                        \
            acc[mi][ni] = __builtin_amdgcn_mfma_f32_32x32x16_bf16(ah[mi], bh[ni], acc[mi][ni], 0, 0, 0); \
            acc[mi][ni] = __builtin_amdgcn_mfma_f32_32x32x16_bf16(ah[mi], bl[ni], acc[mi][ni], 0, 0, 0); \
            acc[mi][ni] = __builtin_amdgcn_mfma_f32_32x32x16_bf16(al[mi], bh[ni], acc[mi][ni], 0, 0, 0); \
        }                                                                       \
    }                                                                           \
} while (0)

    ISSUE(0);   // prologue: 16 loads in flight for stage 0

#pragma unroll
    for (int t = 0; t < 6; ++t) {
        if (t < 5) {
            ISSUE(t + 1);                                      // 16 more, other buffer
            asm volatile("s_waitcnt vmcnt(16)" ::: "memory");  // stage-t loads landed
        } else {
            asm volatile("s_waitcnt vmcnt(0)" ::: "memory");
        }
        __builtin_amdgcn_s_barrier();         // everyone's stage-t loads landed
        __builtin_amdgcn_sched_barrier(0);
        COMPUTE(t);
        asm volatile("s_waitcnt lgkmcnt(0)" ::: "memory");     // my LDS reads done
        __builtin_amdgcn_sched_barrier(0);
        __builtin_amdgcn_s_barrier();         // safe to overwrite this buffer
    }

#undef ISSUE
#undef COMPUTE

    // ---- epilogue: tanh, store x, s = x.a (validated layout from round 2) ----
    const float a0v = a[wn * 64 + fr];
    const float a1v = a[wn * 64 + 32 + fr];

#pragma unroll
    for (int mi = 0; mi < 2; ++mi) {
        float sp[16];
#pragma unroll
        for (int r = 0; r < 16; ++r) sp[r] = 0.0f;
#pragma unroll
        for (int ni = 0; ni < 2; ++ni) {
            const float ac  = (ni == 0) ? a0v : a1v;
            const int   col = wn * 64 + ni * 32 + fr;
#pragma unroll
            for (int r = 0; r < 16; ++r) {
                const int rowl = (r & 3) + 8 * (r >> 2) + 4 * kh;
                const float tv = tanh_fast(acc[mi][ni][r]);
                x[(size_t)(r0 + wm * 64 + mi * 32 + rowl) * EE + col] = tv;
                sp[r] = fmaf(tv, ac, sp[r]);
            }
        }
#pragma unroll
        for (int m = 1; m < 32; m <<= 1)
#pragma unroll
            for (int r = 0; r < 16; ++r) sp[r] += __shfl_xor(sp[r], m, 64);
        if (fr == 0) {
#pragma unroll
            for (int r = 0; r < 16; ++r) {
                const int rowl = (r & 3) + 8 * (r >> 2) + 4 * kh;
                s_red[(wm * 64 + mi * 32 + rowl) * 2 + wn] = sp[r];
            }
        }
    }
    __syncthreads();
    if (tid < 128) s[r0 + tid] = s_red[tid * 2] + s_red[tid * 2 + 1];
}

// ---------------------------------------------------------------------------
// Kernel 2: per-b softmax over full T, mask t<len, weighted sum of x.
// ---------------------------------------------------------------------------
__global__ __launch_bounds__(256)
void k_attn(const float* __restrict__ s, const int* __restrict__ length,
            const float* __restrict__ x, float* __restrict__ v)
{
    __shared__ float sw[TT];
    __shared__ float red[256];

    const int b   = blockIdx.x >> 2;
    const int ec  = blockIdx.x & 3;
    const int tid = threadIdx.x;

    const float s0 = s[b * TT + tid];
    const float s1 = s[b * TT + 256 + tid];

    red[tid] = fmaxf(s0, s1);
    __syncthreads();
    for (int st = 128; st > 0; st >>= 1) {
        if (tid < st) red[tid] = fmaxf(red[tid], red[tid + st]);
        __syncthreads();
    }
    const float mx = red[0];
    __syncthreads();

    const float e0 = __expf(s0 - mx);
    const float e1 = __expf(s1 - mx);
    red[tid] = e0 + e1;
    __syncthreads();
    for (int st = 128; st > 0; st >>= 1) {
        if (tid < st) red[tid] += red[tid + st];
        __syncthreads();
    }
    const float inv = 1.0f / red[0];
    const int   len = length[b];
    __syncthreads();

    sw[tid]       = (tid < len)       ? e0 * inv : 0.0f;
    sw[tid + 256] = (tid + 256 < len) ? e1 * inv : 0.0f;
    __syncthreads();

    const int e  = ec * 32 + (tid & 31);
    const int tp = tid >> 5;
    const float* xb = x + (size_t)b * TT * EE;
    float acc = 0.0f;
#pragma unroll 8
    for (int t = tp; t < TT; t += 8)
        acc = fmaf(sw[t], xb[(size_t)t * EE + e], acc);

    red[tid] = acc;
    __syncthreads();
    if (tid < 32) {
        float r2 = 0.0f;
#pragma unroll
        for (int k = 0; k < 8; ++k) r2 += red[k * 32 + tid];
        v[b * EE + ec * 32 + tid] = r2;
    }
}

// ---------------------------------------------------------------------------
// Kernel 3: out[b][o] = v[b] . out_W[o] + out_b[o]
// ---------------------------------------------------------------------------
__global__ __launch_bounds__(256)
void k_out(const float* __restrict__ v, const float* __restrict__ out_W,
           const float* __restrict__ out_b, float* __restrict__ out)
{
    const int id = blockIdx.x * 256 + threadIdx.x;   // 0..63999
    const int o  = id >> 6;
    const int bb = id & 63;

    const float4* vr = (const float4*)(v + bb * EE);
    const float4* wr = (const float4*)(out_W + o * EE);
    float acc = 0.0f;
#pragma unroll 8
    for (int qq = 0; qq < 32; ++qq) {
        const float4 a4 = vr[qq];
        const float4 b4 = wr[qq];
        acc = fmaf(a4.x, b4.x, acc);
        acc = fmaf(a4.y, b4.y, acc);
        acc = fmaf(a4.z, b4.z, acc);
        acc = fmaf(a4.w, b4.w, acc);
    }
    out[bb * OUTN + o] = acc + out_b[o];
}

extern "C" void kernel_launch(void* const* d_in, const int* in_sizes, int n_in,
                              void* d_out, int out_size, void* d_ws, size_t ws_size,
                              hipStream_t stream)
{
    const int*   starts   = (const int*)d_in[0];
    const int*   paths    = (const int*)d_in[1];
    const int*   ends     = (const int*)d_in[2];
    const int*   length   = (const int*)d_in[3];
    const float* node_emb = (const float*)d_in[4];
    const float* path_emb = (const float*)d_in[5];
    const float* W        = (const float*)d_in[6];
    const float* a        = (const float*)d_in[7];
    const float* out_W    = (const float*)d_in[8];
    const float* out_b    = (const float*)d_in[9];
    float*       out      = (float*)d_out;

    // ws layout: x[32768*128] f32 | s[32768] f32 | v[64*128] f32 | Whg | Wlg
    float* x = (float*)d_ws;
    float* s = x + (size_t)NROWS * EE;
    float* v = s + NROWS;
    unsigned short* Whg = (unsigned short*)(v + BB * EE);      // 6*16384 B
    unsigned short* Wlg = Whg + 6 * 8192;                      // 6*16384 B

    static const int SMEM = 133632;   // 2*32K A + 2*16K Wh + 2*16K Wl + idx + s_red
    hipFuncSetAttribute((const void*)k_gemm_x,
                        hipFuncAttributeMaxDynamicSharedMemorySize, SMEM);

    k_prep<<<192, 256, 0, stream>>>(W, Whg, Wlg);
    k_gemm_x<<<NROWS / 128, 256, SMEM, stream>>>(starts, paths, ends,
                                                 node_emb, path_emb, Whg, Wlg,
                                                 a, x, s);
    k_attn<<<BB * 4, 256, 0, stream>>>(s, length, x, v);
    k_out<<<(BB * OUTN) / 256, 256, 0, stream>>>(v, out_W, out_b, out);
}